// Round 2
// baseline (359.330 us; speedup 1.0000x reference)
//
#include <hip/hip_runtime.h>
#include <hip/hip_bf16.h>

typedef __bf16 bf16_t;
typedef __bf16 bf16x8 __attribute__((ext_vector_type(8)));
typedef __bf16 bf16x4 __attribute__((ext_vector_type(4)));
typedef float f32x4 __attribute__((ext_vector_type(4)));
typedef float f32x16 __attribute__((ext_vector_type(16)));

#define BS 4
#define SL 2048
#define DM 1024
#define NH 16
#define HD 64

static __device__ __forceinline__ bf16_t tobf(float x) { return (bf16_t)x; }

#if __has_builtin(__builtin_amdgcn_exp2f)
#define EXP2(x) __builtin_amdgcn_exp2f(x)
#else
#define EXP2(x) exp2f(x)
#endif

#if __has_builtin(__builtin_amdgcn_cvt_pk_bf16_f32)
typedef __bf16 bf16x2_t __attribute__((ext_vector_type(2)));
static __device__ __forceinline__ uint32_t pack_bf16(float a, float b) {
  union { bf16x2_t v; uint32_t u; } c;
  c.v = __builtin_amdgcn_cvt_pk_bf16_f32(a, b);
  return c.u;
}
#else
static __device__ __forceinline__ uint32_t pack_bf16(float a, float b) {
  union { bf16_t e[2]; uint32_t u; } c;
  c.e[0] = tobf(a); c.e[1] = tobf(b);
  return c.u;
}
#endif

// async global->LDS, 16B per lane; dest = lds_base + lane*16 (wave-uniform base)
static __device__ __forceinline__ void glds16(const void* g, void* l) {
  __builtin_amdgcn_global_load_lds(
      (const __attribute__((address_space(1))) void*)g,
      (__attribute__((address_space(3))) void*)l, 16, 0, 0);
}

// barriers / waits as raw asm with memory clobber: full code-motion fence,
// no compiler-inserted vmcnt(0) drain (rule #18: sched_barrier after waits).
#define BAR()    asm volatile("s_barrier" ::: "memory")
#define WAITV0() asm volatile("s_waitcnt vmcnt(0)" ::: "memory")
#define WAITV4() asm volatile("s_waitcnt vmcnt(4)" ::: "memory")
#define WAITLG() asm volatile("s_waitcnt lgkmcnt(0)" ::: "memory")
#define SCHEDB() __builtin_amdgcn_sched_barrier(0)

// ---------------------------------------------------------------------------
// Weight convert: 4x [1024x1024] fp32 -> bf16 (Wq,Wk,Wv -> concat; Wo)
// ---------------------------------------------------------------------------
__global__ void convert_w_kernel(const float* __restrict__ s0, const float* __restrict__ s1,
                                 const float* __restrict__ s2, const float* __restrict__ s3,
                                 bf16_t* __restrict__ d0, bf16_t* __restrict__ d1,
                                 bf16_t* __restrict__ d2, bf16_t* __restrict__ d3)
{
  const float* s; bf16_t* d;
  switch (blockIdx.y) {
    case 0: s = s0; d = d0; break;
    case 1: s = s1; d = d1; break;
    case 2: s = s2; d = d2; break;
    default: s = s3; d = d3; break;
  }
  int i = (blockIdx.x * 256 + threadIdx.x) * 4;
  float4 v = *(const float4*)(s + i);
  bf16x4 o; o[0] = tobf(v.x); o[1] = tobf(v.y); o[2] = tobf(v.z); o[3] = tobf(v.w);
  *(bf16x4*)(d + i) = o;
}

// ---------------------------------------------------------------------------
// Activation convert: 3x [8192x1024] fp32 -> bf16 concat [query,key_in,value]
// ---------------------------------------------------------------------------
__global__ void convert_a_kernel(const float* __restrict__ q, const float* __restrict__ k,
                                 const float* __restrict__ v, bf16_t* __restrict__ dst)
{
  const float* s = blockIdx.y == 0 ? q : (blockIdx.y == 1 ? k : v);
  bf16_t* d = dst + (size_t)blockIdx.y * ((size_t)BS * SL * DM);
  int i = (blockIdx.x * 256 + threadIdx.x) * 4;
  float4 x = *(const float4*)(s + i);
  bf16x4 o; o[0] = tobf(x.x); o[1] = tobf(x.y); o[2] = tobf(x.z); o[3] = tobf(x.w);
  *(bf16x4*)(d + i) = o;
}

// ---------------------------------------------------------------------------
// Fused QKV GEMM — 256x256 tile, 8-phase schedule, counted vmcnt (T3+T4+T5).
// C_p = A_p[8192,1024] * W_p^T + b_p,  p = blockIdx.y>>2 in {Q,K,V}.
// 512 threads (8 waves, 2M x 4N). K-tile BK=64 split in two K=32 "units";
// 4 rotating 16KB unit-buffers per matrix (128 KiB LDS total).
// Phase (qm,kk): 16 MFMA = half-C x K=32. Stage 1 unit (2 glds) per phase:
//   phase g even -> A-unit g/2+3, g odd -> B-unit (g+5)/2  (lead: A@2u-6, B@2u-5)
// One vmcnt(4) per K-tile boundary (phases 3 mod 4); 2 units stay in flight
// across every barrier. vmcnt(0) only at the T=14 boundary (staging exhausted).
// V-projection epilogue writes Vt[bh][hd][s] transposed (bf16x4 per lane).
// ---------------------------------------------------------------------------
__global__ __launch_bounds__(512, 2) void gemm_qkv_kernel(
    const bf16_t* __restrict__ Aall, const bf16_t* __restrict__ Wcat,
    const float* __restrict__ bq, const float* __restrict__ bk, const float* __restrict__ bvv,
    bf16_t* __restrict__ Qb, bf16_t* __restrict__ Kbo, bf16_t* __restrict__ Vtb)
{
  __shared__ __align__(16) char sMem[131072];  // A units 0..3 | B units 0..3

  const int tid  = threadIdx.x;
  const int wave = tid >> 6;
  const int lane = tid & 63;
  const int l15  = lane & 15;
  const int quad = lane >> 4;
  const int wr   = wave >> 2;            // 0..1 (M)
  const int wc   = wave & 3;             // 0..3 (N)
  const int m0 = blockIdx.x * 256;
  const int nTile = blockIdx.y;          // 0..11
  const int proj = nTile >> 2;
  const int n0 = (nTile & 3) * 256;      // col base within proj
  const int nW = nTile * 256;            // row base in Wcat

  const bf16_t* Af = Aall + (size_t)proj * ((size_t)BS * SL * DM);
  const float* bias = proj == 0 ? bq : (proj == 1 ? bk : bvv);

  // stage one 16KB unit: 256 rows x 32 cols bf16, row = 64B, XOR chunk^(row&3)
  auto stageA = [&](int u) {
    int tu = u >> 1, kk = u & 1;
    char* dst = sMem + (u & 3) * 16384;
#pragma unroll
    for (int g2 = 0; g2 < 2; g2++) {
      int slot = wave * 2 + g2;
      int f = slot * 64 + lane;
      int row = f >> 2;
      int cg = (f & 3) ^ (row & 3);
      glds16(Af + (size_t)(m0 + row) * DM + tu * 64 + kk * 32 + cg * 8,
             dst + slot * 1024);
    }
  };
  auto stageB = [&](int u) {
    int tu = u >> 1, kk = u & 1;
    char* dst = sMem + 65536 + (u & 3) * 16384;
#pragma unroll
    for (int g2 = 0; g2 < 2; g2++) {
      int slot = wave * 2 + g2;
      int f = slot * 64 + lane;
      int row = f >> 2;
      int cg = (f & 3) ^ (row & 3);
      glds16(Wcat + (size_t)(nW + row) * DM + tu * 64 + kk * 32 + cg * 8,
             dst + slot * 1024);
    }
  };

  f32x4 acc[8][4];
#pragma unroll
  for (int i = 0; i < 8; i++)
#pragma unroll
    for (int j = 0; j < 4; j++) acc[i][j] = f32x4{0.f, 0.f, 0.f, 0.f};

  // prologue: units A0,B0,A1,B1,A2,B2; drain tile0 (vmcnt(4) leaves A2,B2 flying)
  stageA(0); stageB(0); stageA(1); stageB(1); stageA(2); stageB(2);
  WAITV4(); SCHEDB();
  BAR();

  bf16x8 b[4];
  for (int T = 0; T < 16; ++T) {
#pragma unroll
    for (int p = 0; p < 4; ++p) {
      const int qm = p & 1, kk = p >> 1;
      const int ubuf = (2 * T + kk) & 3;
      const char* ab = sMem + ubuf * 16384;
      const char* bb = sMem + 65536 + ubuf * 16384;

      bf16x8 a[4];
#pragma unroll
      for (int mf = 0; mf < 4; mf++) {
        int row = wr * 128 + qm * 64 + mf * 16 + l15;
        a[mf] = *(const bf16x8*)(ab + row * 64 + ((quad ^ (row & 3)) * 16));
      }
      if (qm == 0) {
#pragma unroll
        for (int nf = 0; nf < 4; nf++) {
          int row = wc * 64 + nf * 16 + l15;
          b[nf] = *(const bf16x8*)(bb + row * 64 + ((quad ^ (row & 3)) * 16));
        }
      }

      // stage next unit (schedule: A(u)@2u-6, B(u)@2u-5)
      if (p == 0)      { int u = 2 * T + 3; if (u < 32) stageA(u); }
      else if (p == 1) { int u = 2 * T + 3; if (u < 32) stageB(u); }
      else if (p == 2) { int u = 2 * T + 4; if (u < 32) stageA(u); }
      else             { int u = 2 * T + 4; if (u < 32) stageB(u); }

      if (p == 3 && T < 15) {
        if (T == 14) { WAITV0(); } else { WAITV4(); }
        SCHEDB();
      }
      BAR();
      WAITLG(); SCHEDB();
      __builtin_amdgcn_s_setprio(1);
#pragma unroll
      for (int mf = 0; mf < 4; mf++)
#pragma unroll
        for (int nf = 0; nf < 4; nf++)
          acc[qm * 4 + mf][nf] = __builtin_amdgcn_mfma_f32_16x16x32_bf16(
              a[mf], b[nf], acc[qm * 4 + mf][nf], 0, 0, 0);
      __builtin_amdgcn_s_setprio(0);
      BAR();
    }
  }

  if (proj < 2) {
    bf16_t* C = proj == 0 ? Qb : Kbo;
#pragma unroll
    for (int nf = 0; nf < 4; nf++) {
      int col = n0 + wc * 64 + nf * 16 + l15;
      float bv = bias[col];
#pragma unroll
      for (int i = 0; i < 8; i++) {
        int rowb = m0 + wr * 128 + (i >> 2) * 64 + (i & 3) * 16 + quad * 4;
#pragma unroll
        for (int r = 0; r < 4; r++)
          C[(size_t)(rowb + r) * DM + col] = tobf(acc[i][nf][r] + bv);
      }
    }
  } else {
    // V: write transposed Vt[(b*NH+head)*HD+hd][s], 4 consecutive s per lane
#pragma unroll
    for (int nf = 0; nf < 4; nf++) {
      int col = n0 + wc * 64 + nf * 16 + l15;
      float bv = bias[col];
      int head = col >> 6, hd = col & 63;
#pragma unroll
      for (int i = 0; i < 8; i++) {
        int rowb = m0 + wr * 128 + (i >> 2) * 64 + (i & 3) * 16 + quad * 4;
        int bidx = rowb >> 11, s = rowb & (SL - 1);
        bf16x4 o;
#pragma unroll
        for (int r = 0; r < 4; r++) o[r] = tobf(acc[i][nf][r] + bv);
        *(bf16x4*)(Vtb + ((size_t)(bidx * NH + head) * HD + hd) * SL + s) = o;
      }
    }
  }
}

// ---------------------------------------------------------------------------
// Output GEMM: C[8192,1024] fp32 = A bf16 * Wo^T + bo. Dbuf single-barrier.
// ---------------------------------------------------------------------------
__global__ __launch_bounds__(256, 2) void gemm_out_kernel(
    const bf16_t* __restrict__ A, const bf16_t* __restrict__ Bw,
    const float* __restrict__ bias, float* __restrict__ C)
{
  __shared__ __align__(16) char sMem[32768];   // [A0 8K][B0 8K][A1 8K][B1 8K]

  const int tid  = threadIdx.x;
  const int wave = tid >> 6;
  const int lane = tid & 63;
  const int l15  = lane & 15;
  const int quad = lane >> 4;
  const int m0 = blockIdx.x * 128;
  const int n0 = blockIdx.y * 128;
  const int wm = (wave & 1) * 64;
  const int wn = (wave >> 1) * 64;

  auto stage = [&](int r, int k0) {
    char* base = sMem + r * 16384;
#pragma unroll
    for (int t = 0; t < 2; t++) {
      int slot = wave * 2 + t;
      int f = slot * 64 + lane;
      int row = f >> 2;
      int cg = (f & 3) ^ (row & 3);
      glds16(A  + (size_t)(m0 + row) * DM + k0 + cg * 8, base + slot * 1024);
      glds16(Bw + (size_t)(n0 + row) * DM + k0 + cg * 8, base + 8192 + slot * 1024);
    }
  };

  f32x4 acc[4][4];
#pragma unroll
  for (int i = 0; i < 4; i++)
#pragma unroll
    for (int j = 0; j < 4; j++) acc[i][j] = f32x4{0.f, 0.f, 0.f, 0.f};

  stage(0, 0);
  for (int t = 0; t < 32; ++t) {
    __syncthreads();
    if (t < 31) stage((t + 1) & 1, (t + 1) * 32);

    const bf16_t* sA = (const bf16_t*)(sMem + (t & 1) * 16384);
    const bf16_t* sB = sA + 4096;

    bf16x8 af[4], bfr[4];
#pragma unroll
    for (int i = 0; i < 4; i++) {
      int row = wm + i * 16 + l15;
      af[i] = *(const bf16x8*)(sA + row * 32 + (quad ^ (row & 3)) * 8);
    }
#pragma unroll
    for (int j = 0; j < 4; j++) {
      int row = wn + j * 16 + l15;
      bfr[j] = *(const bf16x8*)(sB + row * 32 + (quad ^ (row & 3)) * 8);
    }

#pragma unroll
    for (int i = 0; i < 4; i++)
#pragma unroll
      for (int j = 0; j < 4; j++)
        acc[i][j] = __builtin_amdgcn_mfma_f32_16x16x32_bf16(af[i], bfr[j], acc[i][j], 0, 0, 0);
  }

#pragma unroll
  for (int j = 0; j < 4; j++) {
    int col = n0 + wn + j * 16 + l15;
    float bv = bias[col];
#pragma unroll
    for (int i = 0; i < 4; i++) {
      int rowb = m0 + wm + i * 16 + quad * 4;
#pragma unroll
      for (int r = 0; r < 4; r++)
        C[(size_t)(rowb + r) * DM + col] = acc[i][j][r] + bv;
    }
  }
}

// ---------------------------------------------------------------------------
// Flash attention, S^T form, LDS-staged K/V (glds), double-buffered,
// ONE barrier per 64-key tile. 32x32x16 MFMA; fixed-shift exp2 softmax
// (C-init = -12*log2e, Q scale folds 0.125*log2e); P^T via register shuffles.
// LDS swizzle k(row) = (row + (row>>3)) & 7 balances b128 frag-read banks.
// ---------------------------------------------------------------------------
__global__ __launch_bounds__(256, 4) void attn_kernel(
    const bf16_t* __restrict__ Q, const bf16_t* __restrict__ Kb,
    const bf16_t* __restrict__ Vt, bf16_t* __restrict__ O)
{
  __shared__ __align__(16) char sMem[32768];   // [K0 8K][V0 8K][K1 8K][V1 8K]

  const int tid  = threadIdx.x;
  const int wave = tid >> 6;
  const int lane = tid & 63;
  const int l31  = lane & 31;
  const int h    = lane >> 5;
  const int swl  = l31 & 7;

  const int id  = blockIdx.x;            // 1024 blocks
  const int xcd = id & 7, slot = id >> 3;
  const int bh  = xcd * 8 + (slot >> 4); // 8 bh per XCD -> K/V L2-resident
  const int qi  = slot & 15;
  const int b = bh >> 4, hh = bh & 15;
  const int q0 = qi * 128 + wave * 32;

  auto stage = [&](int r, int k0) {
    char* base = sMem + r * 16384;
#pragma unroll
    for (int t = 0; t < 2; t++) {
      int slot2 = wave * 2 + t;
      int f = slot2 * 64 + lane;
      int row = f >> 3;
      int cg = (f & 7) ^ ((row + (row >> 3)) & 7);
      glds16(Kb + (size_t)(b * SL + k0 + row) * DM + hh * HD + cg * 8,
             base + slot2 * 1024);
      glds16(Vt + ((size_t)bh * HD + row) * SL + k0 + cg * 8,
             base + 8192 + slot2 * 1024);
    }
  };

  // Q B-frags: n=q=l31, k=hd = c*16 + h*8 + j; scale = 0.125 * log2(e)
  bf16x8 qf[4];
  {
    const bf16_t* qp = Q + (size_t)(b * SL + q0 + l31) * DM + hh * HD + h * 8;
#pragma unroll
    for (int c = 0; c < 4; c++) {
      bf16x8 v = *(const bf16x8*)(qp + c * 16);
#pragma unroll
      for (int j = 0; j < 8; j++) v[j] = tobf((float)v[j] * 0.18033688f);
      qf[c] = v;
    }
  }

  f32x16 o_acc[2];
#pragma unroll
  for (int m = 0; m < 2; m++)
#pragma unroll
    for (int r = 0; r < 16; r++) o_acc[m][r] = 0.f;
  float rs0 = 0.f, rs1 = 0.f;

  stage(0, 0);
  for (int t = 0; t < 32; ++t) {
    __syncthreads();                      // stage(t) landed; prev buf reads done
    if (t < 31) stage((t + 1) & 1, (t + 1) * 64);

    const bf16_t* sK = (const bf16_t*)(sMem + (t & 1) * 16384);
    const bf16_t* sV = sK + 4096;

#pragma unroll
    for (int s = 0; s < 2; s++) {
      // S^T[key][q]: A = K rows (key = s*32 + l31)
      int rowK = s * 32 + l31;
      int kkK = (rowK + (rowK >> 3)) & 7;
      bf16x8 kf[4];
#pragma unroll
      for (int c = 0; c < 4; c++)
        kf[c] = *(const bf16x8*)(sK + rowK * 64 + (((c * 2 + h) ^ kkK) * 8));

      f32x16 st;
#pragma unroll
      for (int r = 0; r < 16; r++) st[r] = -17.312340f;   // -12*log2(e)
#pragma unroll
      for (int c = 0; c < 4; c++)
        st = __builtin_amdgcn_mfma_f32_32x32x16_bf16(kf[c], qf[c], st, 0, 0, 0);

      // p = 2^st; row-sum; pack bf16 pairs (reg r = key (r&3)+8*(r>>2)+4h)
      uint32_t w[8];
#pragma unroll
      for (int i = 0; i < 8; i++) {
        float p0 = EXP2(st[2 * i]);
        float p1 = EXP2(st[2 * i + 1]);
        rs0 += p0; rs1 += p1;
        w[i] = pack_bf16(p0, p1);
      }
      // cross-half exchange -> P^T B-frags (layout verified R2/R3)
      uint32_t y0 = (uint32_t)__shfl_xor((int)(h ? w[0] : w[2]), 32);
      uint32_t y1 = (uint32_t)__shfl_xor((int)(h ? w[1] : w[3]), 32);
      uint32_t y2 = (uint32_t)__shfl_xor((int)(h ? w[4] : w[6]), 32);
      uint32_t y3 = (uint32_t)__shfl_xor((int)(h ? w[5] : w[7]), 32);
      union { uint32_t u[4]; bf16x8 v; } pf0, pf1;
      pf0.u[0] = h ? y0   : w[0];
      pf0.u[1] = h ? y1   : w[1];
      pf0.u[2] = h ? w[2] : y0;
      pf0.u[3] = h ? w[3] : y1;
      pf1.u[0] = h ? y2   : w[4];
      pf1.u[1] = h ? y3   : w[5];
      pf1.u[2] = h ? w[6] : y2;
      pf1.u[3] = h ? w[7] : y3;

      // O^T[hd][q] += V^T[hd][key] * P^T
#pragma unroll
      for (int m = 0; m < 2; m++) {
        int rowV = m * 32 + l31;
        int kkV = (rowV + (rowV >> 3)) & 7;
#pragma unroll
        for (int c = 0; c < 2; c++) {
          int chunk = (s * 4 + c * 2 + h) ^ kkV;
          bf16x8 vf = *(const bf16x8*)(sV + rowV * 64 + chunk * 8);
          o_acc[m] = __builtin_amdgcn_mfma_f32_32x32x16_bf16(
              vf, (c ? pf1.v : pf0.v), o_acc[m], 0, 0, 0);
        }
      }
    }
  }

  // epilogue: normalize, transpose O^T->O via per-wave LDS (region 0 free:
  // last tile t=31 used region 1)
  float rs = rs0 + rs1;
  rs += __shfl_xor(rs, 32);
  float inv = 1.f / rs;
  bf16_t* so = (bf16_t*)sMem + wave * 2048;   // 32q x 64hd, 4KB per wave
#pragma unroll
  for (int m = 0; m < 2; m++) {
#pragma unroll
    for (int r = 0; r < 16; r++) {
      int hd = m * 32 + (r & 3) + 8 * (r >> 2) + 4 * h;
      so[l31 * 64 + (((hd >> 3) ^ swl) * 8) + (hd & 7)] = tobf(o_acc[m][r] * inv);
    }
  }
  asm volatile("s_waitcnt lgkmcnt(0)" ::: "memory");   // wave-private region
  {
    int qr = lane >> 1, hf = lane & 1;
    int sw2 = qr & 7;
#pragma unroll
    for (int cc = 0; cc < 4; cc++) {
      int chunk = (hf * 4 + cc) ^ sw2;
      bf16x8 v = *(const bf16x8*)(so + qr * 64 + chunk * 8);
      *(bf16x8*)(O + (size_t)(b * SL + q0 + qr) * DM + hh * HD + hf * 32 + cc * 8) = v;
    }
  }
}

// ---------------------------------------------------------------------------
extern "C" void kernel_launch(void* const* d_in, const int* in_sizes, int n_in,
                              void* d_out, int out_size, void* d_ws, size_t ws_size,
                              hipStream_t stream)
{
  const float* value  = (const float*)d_in[0];
  const float* key_in = (const float*)d_in[1];
  const float* query  = (const float*)d_in[2];
  const float* Wq = (const float*)d_in[3];
  const float* bq = (const float*)d_in[4];
  const float* Wk = (const float*)d_in[5];
  const float* bk = (const float*)d_in[6];
  const float* Wv = (const float*)d_in[7];
  const float* bv = (const float*)d_in[8];
  const float* Wo = (const float*)d_in[9];
  const float* bo = (const float*)d_in[10];

  char* ws = (char*)d_ws;
  const size_t sz  = (size_t)BS * SL * DM * sizeof(bf16_t);  // 16.78 MB
  const size_t wsz = (size_t)DM * DM * sizeof(bf16_t);       // 2 MB
  bf16_t* Qb   = (bf16_t*)(ws + 0 * sz);
  bf16_t* Kb   = (bf16_t*)(ws + 1 * sz);
  bf16_t* Ob   = (bf16_t*)(ws + 2 * sz);
  bf16_t* Vtb  = (bf16_t*)(ws + 3 * sz);
  bf16_t* Wcat = (bf16_t*)(ws + 4 * sz);                     // [3072][1024]
  bf16_t* Wob  = (bf16_t*)(ws + 4 * sz + 3 * wsz);
  bf16_t* Abf  = (bf16_t*)(ws + 4 * sz + 4 * wsz);           // [3][8192][1024]

  const int M = BS * SL;  // 8192

  convert_w_kernel<<<dim3(1024, 4), 256, 0, stream>>>(
      Wq, Wk, Wv, Wo, Wcat, Wcat + DM * DM, Wcat + 2 * DM * DM, Wob);

  convert_a_kernel<<<dim3(M * DM / 1024, 3), 256, 0, stream>>>(
      query, key_in, value, Abf);

  gemm_qkv_kernel<<<dim3(M / 256, 12), 512, 0, stream>>>(
      Abf, Wcat, bq, bk, bv, Qb, Kb, Vtb);

  attn_kernel<<<dim3(SL / 128 * BS * NH), 256, 0, stream>>>(Qb, Kb, Vtb, Ob);

  gemm_out_kernel<<<dim3(M / 128, DM / 128), 256, 0, stream>>>(Ob, Wob, bo, (float*)d_out);
}

// Round 3
// 332.253 us; speedup vs baseline: 1.0815x; 1.0815x over previous
//
#include <hip/hip_runtime.h>
#include <hip/hip_bf16.h>

typedef __bf16 bf16_t;
typedef __bf16 bf16x8 __attribute__((ext_vector_type(8)));
typedef __bf16 bf16x4 __attribute__((ext_vector_type(4)));
typedef float f32x4 __attribute__((ext_vector_type(4)));
typedef float f32x16 __attribute__((ext_vector_type(16)));

#define BS 4
#define SL 2048
#define DM 1024
#define NH 16
#define HD 64

static __device__ __forceinline__ bf16_t tobf(float x) { return (bf16_t)x; }

#if __has_builtin(__builtin_amdgcn_exp2f)
#define EXP2(x) __builtin_amdgcn_exp2f(x)
#else
#define EXP2(x) exp2f(x)
#endif

#if __has_builtin(__builtin_amdgcn_cvt_pk_bf16_f32)
typedef __bf16 bf16x2_t __attribute__((ext_vector_type(2)));
static __device__ __forceinline__ uint32_t pack_bf16(float a, float b) {
  union { bf16x2_t v; uint32_t u; } c;
  c.v = __builtin_amdgcn_cvt_pk_bf16_f32(a, b);
  return c.u;
}
#else
static __device__ __forceinline__ uint32_t pack_bf16(float a, float b) {
  union { bf16_t e[2]; uint32_t u; } c;
  c.e[0] = tobf(a); c.e[1] = tobf(b);
  return c.u;
}
#endif

// lane^32 half-swap: a' = [a.lo, b.lo], b' = [a.hi, b.hi]  (T12)
static __device__ __forceinline__ void permswap(uint32_t& a, uint32_t& b) {
  asm("v_permlane32_swap_b32 %0, %1" : "+v"(a), "+v"(b));
}

// async global->LDS, 16B per lane; dest = lds_base + lane*16 (wave-uniform base)
static __device__ __forceinline__ void glds16(const void* g, void* l) {
  __builtin_amdgcn_global_load_lds(
      (const __attribute__((address_space(1))) void*)g,
      (__attribute__((address_space(3))) void*)l, 16, 0, 0);
}

#define BAR()    asm volatile("s_barrier" ::: "memory")
#define WAITV0() asm volatile("s_waitcnt vmcnt(0)" ::: "memory")
#define WAITV3() asm volatile("s_waitcnt vmcnt(3)" ::: "memory")
#define WAITV6() asm volatile("s_waitcnt vmcnt(6)" ::: "memory")
#define WAITLG() asm volatile("s_waitcnt lgkmcnt(0)" ::: "memory")
#define SCHEDB() __builtin_amdgcn_sched_barrier(0)

// ---------------------------------------------------------------------------
// Weight convert: 4x [1024x1024] fp32 -> bf16 (Wq,Wk,Wv -> concat; Wo)
// ---------------------------------------------------------------------------
__global__ void convert_w_kernel(const float* __restrict__ s0, const float* __restrict__ s1,
                                 const float* __restrict__ s2, const float* __restrict__ s3,
                                 bf16_t* __restrict__ d0, bf16_t* __restrict__ d1,
                                 bf16_t* __restrict__ d2, bf16_t* __restrict__ d3)
{
  const float* s; bf16_t* d;
  switch (blockIdx.y) {
    case 0: s = s0; d = d0; break;
    case 1: s = s1; d = d1; break;
    case 2: s = s2; d = d2; break;
    default: s = s3; d = d3; break;
  }
  int i = (blockIdx.x * 256 + threadIdx.x) * 4;
  float4 v = *(const float4*)(s + i);
  bf16x4 o; o[0] = tobf(v.x); o[1] = tobf(v.y); o[2] = tobf(v.z); o[3] = tobf(v.w);
  *(bf16x4*)(d + i) = o;
}

// ---------------------------------------------------------------------------
// Activation convert: 3x [8192x1024] fp32 -> bf16 concat [query,key_in,value]
// ---------------------------------------------------------------------------
__global__ void convert_a_kernel(const float* __restrict__ q, const float* __restrict__ k,
                                 const float* __restrict__ v, bf16_t* __restrict__ dst)
{
  const float* s = blockIdx.y == 0 ? q : (blockIdx.y == 1 ? k : v);
  bf16_t* d = dst + (size_t)blockIdx.y * ((size_t)BS * SL * DM);
  int i = (blockIdx.x * 256 + threadIdx.x) * 4;
  float4 x = *(const float4*)(s + i);
  bf16x4 o; o[0] = tobf(x.x); o[1] = tobf(x.y); o[2] = tobf(x.z); o[3] = tobf(x.w);
  *(bf16x4*)(d + i) = o;
}

// ---------------------------------------------------------------------------
// Fused QKV GEMM — 128x256 tile, counted-vmcnt phase schedule (T3+T4+T5).
// Grid 64x12 = 768 blocks = EXACTLY 3 rounds of 256 CUs (fixes R1's 1.5-round
// 25% idle). 512 thr (8 waves: 2M x 4N, 64x64 acc each). K unit = 32 cols;
// A-unit 8KB, B-unit 16KB, 4 rotating buffers each -> 96 KiB LDS.
// Per phase g: frag-read unit g, stage unit g+3 (3 glds/wave), vmcnt(6)
// [2 units / 6 glds stay in flight across every barrier], BAR, lgkm, 16 MFMA,
// BAR. Tail peeled: g=29 vmcnt(3), g=30 vmcnt(0), g=31 no wait.
// V-projection epilogue writes Vt[bh][hd][s] transposed (bf16x4 per lane).
// ---------------------------------------------------------------------------
__global__ __launch_bounds__(512, 2) void gemm_qkv_kernel(
    const bf16_t* __restrict__ Aall, const bf16_t* __restrict__ Wcat,
    const float* __restrict__ bq, const float* __restrict__ bk, const float* __restrict__ bvv,
    bf16_t* __restrict__ Qb, bf16_t* __restrict__ Kbo, bf16_t* __restrict__ Vtb)
{
  __shared__ __align__(16) char sMem[98304];  // A units x4 (32K) | B units x4 (64K)

  const int tid  = threadIdx.x;
  const int wave = tid >> 6;
  const int lane = tid & 63;
  const int l15  = lane & 15;
  const int quad = lane >> 4;
  const int wr   = wave >> 2;            // 0..1 (M, 64 rows each)
  const int wc   = wave & 3;             // 0..3 (N, 64 cols each)
  const int m0 = blockIdx.x * 128;
  const int nTile = blockIdx.y;          // 0..11
  const int proj = nTile >> 2;
  const int n0 = (nTile & 3) * 256;      // col base within proj
  const int nW = nTile * 256;            // row base in Wcat

  const bf16_t* Af = Aall + (size_t)proj * ((size_t)BS * SL * DM);
  const float* bias = proj == 0 ? bq : (proj == 1 ? bk : bvv);

  auto stageU = [&](int u) {
    int k0 = u * 32;
    {   // A: 128 rows x 32 cols = 8KB, 1 glds/wave
      char* dst = sMem + (u & 3) * 8192;
      int f = wave * 64 + lane;
      int row = f >> 2;
      int cg = (f & 3) ^ (row & 3);
      glds16(Af + (size_t)(m0 + row) * DM + k0 + cg * 8, dst + wave * 1024);
    }
    {   // B: 256 rows x 32 cols = 16KB, 2 glds/wave
      char* dst = sMem + 32768 + (u & 3) * 16384;
#pragma unroll
      for (int g2 = 0; g2 < 2; g2++) {
        int slot = wave * 2 + g2;
        int f = slot * 64 + lane;
        int row = f >> 2;
        int cg = (f & 3) ^ (row & 3);
        glds16(Wcat + (size_t)(nW + row) * DM + k0 + cg * 8, dst + slot * 1024);
      }
    }
  };

  f32x4 acc[4][4];
#pragma unroll
  for (int i = 0; i < 4; i++)
#pragma unroll
    for (int j = 0; j < 4; j++) acc[i][j] = f32x4{0.f, 0.f, 0.f, 0.f};

  stageU(0); stageU(1); stageU(2);
  WAITV6(); SCHEDB();
  BAR();

  auto phase = [&](int g, int stageu, int waitn) {
    const char* ab = sMem + (g & 3) * 8192;
    const char* bb = sMem + 32768 + (g & 3) * 16384;
    bf16x8 a[4], b[4];
#pragma unroll
    for (int mf = 0; mf < 4; mf++) {
      int row = wr * 64 + mf * 16 + l15;
      a[mf] = *(const bf16x8*)(ab + row * 64 + ((quad ^ (row & 3)) * 16));
    }
#pragma unroll
    for (int nf = 0; nf < 4; nf++) {
      int row = wc * 64 + nf * 16 + l15;
      b[nf] = *(const bf16x8*)(bb + row * 64 + ((quad ^ (row & 3)) * 16));
    }
    if (stageu >= 0) stageU(stageu);
    if (waitn == 6)      { WAITV6(); SCHEDB(); }
    else if (waitn == 3) { WAITV3(); SCHEDB(); }
    else if (waitn == 0) { WAITV0(); SCHEDB(); }
    BAR();
    WAITLG(); SCHEDB();
    __builtin_amdgcn_s_setprio(1);
#pragma unroll
    for (int mf = 0; mf < 4; mf++)
#pragma unroll
      for (int nf = 0; nf < 4; nf++)
        acc[mf][nf] = __builtin_amdgcn_mfma_f32_16x16x32_bf16(
            a[mf], b[nf], acc[mf][nf], 0, 0, 0);
    __builtin_amdgcn_s_setprio(0);
    BAR();
  };

#pragma unroll 4
  for (int g = 0; g < 28; ++g) phase(g, g + 3, 6);
  phase(28, 31, 6);
  phase(29, -1, 3);
  phase(30, -1, 0);
  phase(31, -1, -1);

  if (proj < 2) {
    bf16_t* C = proj == 0 ? Qb : Kbo;
#pragma unroll
    for (int nf = 0; nf < 4; nf++) {
      int col = n0 + wc * 64 + nf * 16 + l15;
      float bv = bias[col];
#pragma unroll
      for (int mf = 0; mf < 4; mf++) {
        int rowb = m0 + wr * 64 + mf * 16 + quad * 4;
#pragma unroll
        for (int r = 0; r < 4; r++)
          C[(size_t)(rowb + r) * DM + col] = tobf(acc[mf][nf][r] + bv);
      }
    }
  } else {
    // V: write transposed Vt[(b*NH+head)*HD+hd][s], 4 consecutive s per lane
#pragma unroll
    for (int nf = 0; nf < 4; nf++) {
      int col = n0 + wc * 64 + nf * 16 + l15;
      float bv = bias[col];
      int head = col >> 6, hd = col & 63;
#pragma unroll
      for (int mf = 0; mf < 4; mf++) {
        int rowb = m0 + wr * 64 + mf * 16 + quad * 4;
        int bidx = rowb >> 11, s = rowb & (SL - 1);
        bf16x4 o;
#pragma unroll
        for (int r = 0; r < 4; r++) o[r] = tobf(acc[mf][nf][r] + bv);
        *(bf16x4*)(Vtb + ((size_t)(bidx * NH + head) * HD + hd) * SL + s) = o;
      }
    }
  }
}

// ---------------------------------------------------------------------------
// Output GEMM: C[8192,1024] fp32 = A bf16 * Wo^T + bo.
// Same 128x256 counted-vmcnt template; grid 64x4 = 256 blocks = 1 exact round.
// ---------------------------------------------------------------------------
__global__ __launch_bounds__(512, 2) void gemm_out_kernel(
    const bf16_t* __restrict__ A, const bf16_t* __restrict__ Bw,
    const float* __restrict__ bias, float* __restrict__ C)
{
  __shared__ __align__(16) char sMem[98304];

  const int tid  = threadIdx.x;
  const int wave = tid >> 6;
  const int lane = tid & 63;
  const int l15  = lane & 15;
  const int quad = lane >> 4;
  const int wr   = wave >> 2;
  const int wc   = wave & 3;
  const int m0 = blockIdx.x * 128;
  const int n0 = blockIdx.y * 256;

  auto stageU = [&](int u) {
    int k0 = u * 32;
    {
      char* dst = sMem + (u & 3) * 8192;
      int f = wave * 64 + lane;
      int row = f >> 2;
      int cg = (f & 3) ^ (row & 3);
      glds16(A + (size_t)(m0 + row) * DM + k0 + cg * 8, dst + wave * 1024);
    }
    {
      char* dst = sMem + 32768 + (u & 3) * 16384;
#pragma unroll
      for (int g2 = 0; g2 < 2; g2++) {
        int slot = wave * 2 + g2;
        int f = slot * 64 + lane;
        int row = f >> 2;
        int cg = (f & 3) ^ (row & 3);
        glds16(Bw + (size_t)(n0 + row) * DM + k0 + cg * 8, dst + slot * 1024);
      }
    }
  };

  f32x4 acc[4][4];
#pragma unroll
  for (int i = 0; i < 4; i++)
#pragma unroll
    for (int j = 0; j < 4; j++) acc[i][j] = f32x4{0.f, 0.f, 0.f, 0.f};

  stageU(0); stageU(1); stageU(2);
  WAITV6(); SCHEDB();
  BAR();

  auto phase = [&](int g, int stageu, int waitn) {
    const char* ab = sMem + (g & 3) * 8192;
    const char* bb = sMem + 32768 + (g & 3) * 16384;
    bf16x8 a[4], b[4];
#pragma unroll
    for (int mf = 0; mf < 4; mf++) {
      int row = wr * 64 + mf * 16 + l15;
      a[mf] = *(const bf16x8*)(ab + row * 64 + ((quad ^ (row & 3)) * 16));
    }
#pragma unroll
    for (int nf = 0; nf < 4; nf++) {
      int row = wc * 64 + nf * 16 + l15;
      b[nf] = *(const bf16x8*)(bb + row * 64 + ((quad ^ (row & 3)) * 16));
    }
    if (stageu >= 0) stageU(stageu);
    if (waitn == 6)      { WAITV6(); SCHEDB(); }
    else if (waitn == 3) { WAITV3(); SCHEDB(); }
    else if (waitn == 0) { WAITV0(); SCHEDB(); }
    BAR();
    WAITLG(); SCHEDB();
    __builtin_amdgcn_s_setprio(1);
#pragma unroll
    for (int mf = 0; mf < 4; mf++)
#pragma unroll
      for (int nf = 0; nf < 4; nf++)
        acc[mf][nf] = __builtin_amdgcn_mfma_f32_16x16x32_bf16(
            a[mf], b[nf], acc[mf][nf], 0, 0, 0);
    __builtin_amdgcn_s_setprio(0);
    BAR();
  };

#pragma unroll 4
  for (int g = 0; g < 28; ++g) phase(g, g + 3, 6);
  phase(28, 31, 6);
  phase(29, -1, 3);
  phase(30, -1, 0);
  phase(31, -1, -1);

#pragma unroll
  for (int nf = 0; nf < 4; nf++) {
    int col = n0 + wc * 64 + nf * 16 + l15;
    float bv = bias[col];
#pragma unroll
    for (int mf = 0; mf < 4; mf++) {
      int rowb = m0 + wr * 64 + mf * 16 + quad * 4;
#pragma unroll
      for (int r = 0; r < 4; r++)
        C[(size_t)(rowb + r) * DM + col] = acc[mf][nf][r] + bv;
    }
  }
}

// ---------------------------------------------------------------------------
// Flash attention, S^T form, LDS-staged K/V (glds), double-buffered,
// ONE barrier per 64-key tile. 32x32x16 MFMA; fixed-shift exp2 softmax
// (C-init = -12*log2e, Q scale folds 0.125*log2e); P^T via permlane32_swap
// (replaces shfl_xor + 16 selects; T12). setprio(1) around MFMA clusters.
// LDS swizzle k(row) = (row + (row>>3)) & 7 balances b128 frag-read banks.
// ---------------------------------------------------------------------------
__global__ __launch_bounds__(256, 4) void attn_kernel(
    const bf16_t* __restrict__ Q, const bf16_t* __restrict__ Kb,
    const bf16_t* __restrict__ Vt, bf16_t* __restrict__ O)
{
  __shared__ __align__(16) char sMem[32768];   // [K0 8K][V0 8K][K1 8K][V1 8K]

  const int tid  = threadIdx.x;
  const int wave = tid >> 6;
  const int lane = tid & 63;
  const int l31  = lane & 31;
  const int h    = lane >> 5;
  const int swl  = l31 & 7;

  const int id  = blockIdx.x;            // 1024 blocks
  const int xcd = id & 7, slot = id >> 3;
  const int bh  = xcd * 8 + (slot >> 4); // 8 bh per XCD -> K/V L2-resident
  const int qi  = slot & 15;
  const int b = bh >> 4, hh = bh & 15;
  const int q0 = qi * 128 + wave * 32;

  auto stage = [&](int r, int k0) {
    char* base = sMem + r * 16384;
#pragma unroll
    for (int t = 0; t < 2; t++) {
      int slot2 = wave * 2 + t;
      int f = slot2 * 64 + lane;
      int row = f >> 3;
      int cg = (f & 7) ^ ((row + (row >> 3)) & 7);
      glds16(Kb + (size_t)(b * SL + k0 + row) * DM + hh * HD + cg * 8,
             base + slot2 * 1024);
      glds16(Vt + ((size_t)bh * HD + row) * SL + k0 + cg * 8,
             base + 8192 + slot2 * 1024);
    }
  };

  // Q B-frags: n=q=l31, k=hd = c*16 + h*8 + j; scale = 0.125 * log2(e)
  bf16x8 qf[4];
  {
    const bf16_t* qp = Q + (size_t)(b * SL + q0 + l31) * DM + hh * HD + h * 8;
#pragma unroll
    for (int c = 0; c < 4; c++) {
      bf16x8 v = *(const bf16x8*)(qp + c * 16);
#pragma unroll
      for (int j = 0; j < 8; j++) v[j] = tobf((float)v[j] * 0.18033688f);
      qf[c] = v;
    }
  }

  f32x16 o_acc[2];
#pragma unroll
  for (int m = 0; m < 2; m++)
#pragma unroll
    for (int r = 0; r < 16; r++) o_acc[m][r] = 0.f;
  float rs0 = 0.f, rs1 = 0.f;

  stage(0, 0);
  for (int t = 0; t < 32; ++t) {
    __syncthreads();                      // stage(t) landed; prev buf reads done
    if (t < 31) stage((t + 1) & 1, (t + 1) * 64);

    const bf16_t* sK = (const bf16_t*)(sMem + (t & 1) * 16384);
    const bf16_t* sV = sK + 4096;

#pragma unroll
    for (int s = 0; s < 2; s++) {
      // S^T[key][q]: A = K rows (key = s*32 + l31)
      int rowK = s * 32 + l31;
      int kkK = (rowK + (rowK >> 3)) & 7;
      bf16x8 kf[4];
#pragma unroll
      for (int c = 0; c < 4; c++)
        kf[c] = *(const bf16x8*)(sK + rowK * 64 + (((c * 2 + h) ^ kkK) * 8));

      f32x16 st;
#pragma unroll
      for (int r = 0; r < 16; r++) st[r] = -17.312340f;   // -12*log2(e)
      __builtin_amdgcn_s_setprio(1);
#pragma unroll
      for (int c = 0; c < 4; c++)
        st = __builtin_amdgcn_mfma_f32_32x32x16_bf16(kf[c], qf[c], st, 0, 0, 0);
      __builtin_amdgcn_s_setprio(0);

      // p = 2^st; row-sum; pack bf16 pairs (reg r = key (r&3)+8*(r>>2)+4h)
      uint32_t w[8];
#pragma unroll
      for (int i = 0; i < 8; i++) {
        float p0 = EXP2(st[2 * i]);
        float p1 = EXP2(st[2 * i + 1]);
        rs0 += p0; rs1 += p1;
        w[i] = pack_bf16(p0, p1);
      }
      // cross-half exchange -> P^T B-frags via permlane32_swap:
      // swap(w0,w2): w0'=[w0.lo,w2.lo] (=pf0.u[0]), w2'=[w0.hi,w2.hi] (=pf0.u[2])
      union { uint32_t u[4]; bf16x8 v; } pf0, pf1;
      {
        uint32_t a0 = w[0], b0 = w[2]; permswap(a0, b0);
        uint32_t a1 = w[1], b1 = w[3]; permswap(a1, b1);
        uint32_t a2 = w[4], b2 = w[6]; permswap(a2, b2);
        uint32_t a3 = w[5], b3 = w[7]; permswap(a3, b3);
        pf0.u[0] = a0; pf0.u[1] = a1; pf0.u[2] = b0; pf0.u[3] = b1;
        pf1.u[0] = a2; pf1.u[1] = a3; pf1.u[2] = b2; pf1.u[3] = b3;
      }

      // O^T[hd][q] += V^T[hd][key] * P^T
      __builtin_amdgcn_s_setprio(1);
#pragma unroll
      for (int m = 0; m < 2; m++) {
        int rowV = m * 32 + l31;
        int kkV = (rowV + (rowV >> 3)) & 7;
#pragma unroll
        for (int c = 0; c < 2; c++) {
          int chunk = (s * 4 + c * 2 + h) ^ kkV;
          bf16x8 vf = *(const bf16x8*)(sV + rowV * 64 + chunk * 8);
          o_acc[m] = __builtin_amdgcn_mfma_f32_32x32x16_bf16(
              vf, (c ? pf1.v : pf0.v), o_acc[m], 0, 0, 0);
        }
      }
      __builtin_amdgcn_s_setprio(0);
    }
  }

  // epilogue: normalize, transpose O^T->O via per-wave LDS (region 0 free:
  // last tile t=31 used region 1)
  float rs = rs0 + rs1;
  rs += __shfl_xor(rs, 32);
  float inv = 1.f / rs;
  bf16_t* so = (bf16_t*)sMem + wave * 2048;   // 32q x 64hd, 4KB per wave
#pragma unroll
  for (int m = 0; m < 2; m++) {
#pragma unroll
    for (int r = 0; r < 16; r++) {
      int hd = m * 32 + (r & 3) + 8 * (r >> 2) + 4 * h;
      so[l31 * 64 + (((hd >> 3) ^ swl) * 8) + (hd & 7)] = tobf(o_acc[m][r] * inv);
    }
  }
  asm volatile("s_waitcnt lgkmcnt(0)" ::: "memory");   // wave-private region
  {
    int qr = lane >> 1, hf = lane & 1;
    int sw2 = qr & 7;
#pragma unroll
    for (int cc = 0; cc < 4; cc++) {
      int chunk = (hf * 4 + cc) ^ sw2;
      bf16x8 v = *(const bf16x8*)(so + qr * 64 + chunk * 8);
      *(bf16x8*)(O + (size_t)(b * SL + q0 + qr) * DM + hh * HD + hf * 32 + cc * 8) = v;
    }
  }
}

// ---------------------------------------------------------------------------
extern "C" void kernel_launch(void* const* d_in, const int* in_sizes, int n_in,
                              void* d_out, int out_size, void* d_ws, size_t ws_size,
                              hipStream_t stream)
{
  const float* value  = (const float*)d_in[0];
  const float* key_in = (const float*)d_in[1];
  const float* query  = (const float*)d_in[2];
  const float* Wq = (const float*)d_in[3];
  const float* bq = (const float*)d_in[4];
  const float* Wk = (const float*)d_in[5];
  const float* bk = (const float*)d_in[6];
  const float* Wv = (const float*)d_in[7];
  const float* bv = (const float*)d_in[8];
  const float* Wo = (const float*)d_in[9];
  const float* bo = (const float*)d_in[10];

  char* ws = (char*)d_ws;
  const size_t sz  = (size_t)BS * SL * DM * sizeof(bf16_t);  // 16.78 MB
  const size_t wsz = (size_t)DM * DM * sizeof(bf16_t);       // 2 MB
  bf16_t* Qb   = (bf16_t*)(ws + 0 * sz);
  bf16_t* Kb   = (bf16_t*)(ws + 1 * sz);
  bf16_t* Ob   = (bf16_t*)(ws + 2 * sz);
  bf16_t* Vtb  = (bf16_t*)(ws + 3 * sz);
  bf16_t* Wcat = (bf16_t*)(ws + 4 * sz);                     // [3072][1024]
  bf16_t* Wob  = (bf16_t*)(ws + 4 * sz + 3 * wsz);
  bf16_t* Abf  = (bf16_t*)(ws + 4 * sz + 4 * wsz);           // [3][8192][1024]

  const int M = BS * SL;  // 8192

  convert_w_kernel<<<dim3(1024, 4), 256, 0, stream>>>(
      Wq, Wk, Wv, Wo, Wcat, Wcat + DM * DM, Wcat + 2 * DM * DM, Wob);

  convert_a_kernel<<<dim3(M * DM / 1024, 3), 256, 0, stream>>>(
      query, key_in, value, Abf);

  gemm_qkv_kernel<<<dim3(M / 128, 12), 512, 0, stream>>>(
      Abf, Wcat, bq, bk, bv, Qb, Kb, Vtb);

  attn_kernel<<<dim3(SL / 128 * BS * NH), 256, 0, stream>>>(Qb, Kb, Vtb, Ob);

  gemm_out_kernel<<<dim3(M / 128, DM / 256), 512, 0, stream>>>(Ob, Wob, bo, (float*)d_out);
}